// Round 22
// baseline (611.624 us; speedup 1.0000x reference)
//
#include <hip/hip_runtime.h>
#include <hip/hip_bf16.h>
#include <stdint.h>
#include <math.h>

#define T_TOK 8192
#define DDIM  1024
#define HDIM  512
#define NEXP  64
#define TOPK  8
#define CHUNKS 16

typedef __bf16 bf16x8 __attribute__((ext_vector_type(8)));
typedef float  f32x4  __attribute__((ext_vector_type(4)));

__device__ __forceinline__ void load_lds16(const void* gp, void* lp){
  __builtin_amdgcn_global_load_lds(
      (__attribute__((address_space(1))) void*)(uintptr_t)gp,
      (__attribute__((address_space(3))) void*)lp, 16, 0, 0);
}

__device__ __forceinline__ unsigned short f2bfbits(float f){
  union { __bf16 b; unsigned short u; } cv; cv.b = (__bf16)f; return cv.u;
}
__device__ __forceinline__ float bf2f(unsigned short s){
  unsigned int u = ((unsigned int)s) << 16; return __uint_as_float(u);
}

// counted waits ("memory" clobber orders all memory ops incl. LDS reads/gload_lds)
#define VM6() asm volatile("s_waitcnt vmcnt(6)" ::: "memory")
#define VM4() asm volatile("s_waitcnt vmcnt(4)" ::: "memory")
#define VM2() asm volatile("s_waitcnt vmcnt(2)" ::: "memory")
#define VM0() asm volatile("s_waitcnt vmcnt(0)" ::: "memory")
#define BAR() __builtin_amdgcn_s_barrier()
#define SB0() __builtin_amdgcn_sched_barrier(0)

// ------- merged transpose+convert for BOTH weights, 64x64 tiles -------
__global__ __launch_bounds__(256) void k_transpose_both(const float* __restrict__ Wdown,
                                                        const float* __restrict__ Wup,
                                                        __bf16* __restrict__ wdownT,
                                                        __bf16* __restrict__ wupT){
  __shared__ float tile[64][65];
  const int b = blockIdx.x;
  const float* src; __bf16* dst; int R, C, c0, r0, z;
  if (b < 8192){
    z = b >> 7; int tt = b & 127;
    c0 = (tt & 15) << 6; r0 = (tt >> 4) << 6;
    src = Wdown; dst = wdownT; R = HDIM; C = DDIM;
  } else {
    int bb = b - 8192;
    z = bb >> 7; int tt = bb & 127;
    c0 = (tt & 7) << 6; r0 = (tt >> 3) << 6;
    src = Wup; dst = wupT; R = DDIM; C = HDIM;
  }
  const float* s = src + (size_t)z * R * C;
  __bf16*      d = dst + (size_t)z * R * C;
  const int t = threadIdx.x;
  const int rrow = t >> 4, rchunk = t & 15;
  #pragma unroll
  for (int rep = 0; rep < 4; rep++){
    int r = rrow + (rep << 4);
    float4 v = *(const float4*)(s + (size_t)(r0 + r) * C + c0 + (rchunk << 2));
    tile[(rchunk << 2) + 0][r] = v.x;
    tile[(rchunk << 2) + 1][r] = v.y;
    tile[(rchunk << 2) + 2][r] = v.z;
    tile[(rchunk << 2) + 3][r] = v.w;
  }
  __syncthreads();
  const int wc = t >> 3, wj = t & 7;
  #pragma unroll
  for (int rep = 0; rep < 2; rep++){
    int c = wc + (rep << 5);
    bf16x8 o;
    #pragma unroll
    for (int sidx = 0; sidx < 8; sidx++)
      o[sidx] = (__bf16)tile[c][(wj << 3) + sidx];
    *(bf16x8*)(d + (size_t)(c0 + c) * R + r0 + (wj << 3)) = o;
  }
}

// ---------------- gate GEMM + fused x->bf16 ----------------
__global__ __launch_bounds__(256) void k_gate(const float* __restrict__ x,
                                              const float* __restrict__ Wg,
                                              float* __restrict__ logits,
                                              __bf16* __restrict__ xb){
  __shared__ float xs[32][64];
  __shared__ float ws[32][64];
  const int tid = threadIdx.x;
  const int m0  = blockIdx.x * 64;
  const int tm  = (tid >> 4) << 2;
  const int tn  = (tid & 15) << 2;
  const int sr  = tid >> 2;
  const int sc  = tid & 3;
  double acc[4][4];
  #pragma unroll
  for (int i=0;i<4;i++)
    #pragma unroll
    for (int j=0;j<4;j++) acc[i][j]=0.0;

  for (int k0 = 0; k0 < DDIM; k0 += 32){
    {
      const float4* g = (const float4*)(Wg + (size_t)k0 * 64);
      float4* l = (float4*)&ws[0][0];
      l[tid]       = g[tid];
      l[tid + 256] = g[tid + 256];
    }
    {
      const float* g = x + (size_t)(m0 + sr) * DDIM + k0 + sc * 8;
      float4 a = *(const float4*)g;
      float4 b = *(const float4*)(g + 4);
      xs[sc*8+0][sr]=a.x; xs[sc*8+1][sr]=a.y; xs[sc*8+2][sr]=a.z; xs[sc*8+3][sr]=a.w;
      xs[sc*8+4][sr]=b.x; xs[sc*8+5][sr]=b.y; xs[sc*8+6][sr]=b.z; xs[sc*8+7][sr]=b.w;
      bf16x8 o;
      o[0]=(__bf16)a.x; o[1]=(__bf16)a.y; o[2]=(__bf16)a.z; o[3]=(__bf16)a.w;
      o[4]=(__bf16)b.x; o[5]=(__bf16)b.y; o[6]=(__bf16)b.z; o[7]=(__bf16)b.w;
      *(bf16x8*)(xb + (size_t)(m0 + sr) * DDIM + k0 + sc * 8) = o;
    }
    __syncthreads();
    for (int k = 0; k < 32; k++){
      float4 a4 = *(const float4*)&xs[k][tm];
      float4 b4 = *(const float4*)&ws[k][tn];
      float av[4] = {a4.x,a4.y,a4.z,a4.w};
      float bv[4] = {b4.x,b4.y,b4.z,b4.w};
      #pragma unroll
      for (int i=0;i<4;i++)
        #pragma unroll
        for (int j=0;j<4;j++)
          acc[i][j] += (double)av[i] * (double)bv[j];
    }
    __syncthreads();
  }
  #pragma unroll
  for (int i=0;i<4;i++){
    float4 o = make_float4((float)acc[i][0],(float)acc[i][1],(float)acc[i][2],(float)acc[i][3]);
    *(float4*)&logits[(size_t)(m0 + tm + i) * 64 + tn] = o;
  }
}

// ---------------- top-8 + softmax (wave per token) ----------------
__global__ __launch_bounds__(256) void k_topk(const float* __restrict__ logits,
                                              int* __restrict__ tk_idx,
                                              float* __restrict__ tk_w){
  const int lane = threadIdx.x & 63;
  const int t    = blockIdx.x * 4 + (threadIdx.x >> 6);
  float v = logits[(size_t)t * 64 + lane];
  const int myi = lane;
  float mv[8]; int mi[8];
  #pragma unroll
  for (int k = 0; k < 8; k++){
    float bv = v; int bi = myi;
    #pragma unroll
    for (int off = 32; off > 0; off >>= 1){
      float ov = __shfl_xor(bv, off, 64);
      int   oi = __shfl_xor(bi, off, 64);
      if (ov > bv || (ov == bv && oi < bi)){ bv = ov; bi = oi; }
    }
    mv[k] = bv; mi[k] = bi;
    if (bi == myi) v = -INFINITY;
  }
  float w[8]; float s = 0.f;
  #pragma unroll
  for (int k = 0; k < 8; k++){ w[k] = expf(mv[k] - mv[0]); s += w[k]; }
  float inv = 1.0f / s;
  if (lane == 0){
    #pragma unroll
    for (int k = 0; k < 8; k++){
      tk_idx[(size_t)t * 8 + k] = mi[k];
      tk_w [(size_t)t * 8 + k] = w[k] * inv;
    }
  }
}

// ---------------- per-chunk histogram ----------------
__global__ __launch_bounds__(256) void k_hist(const int* __restrict__ tk_idx,
                                              int* __restrict__ g_hist){
  __shared__ int h[4][64];
  const int tid = threadIdx.x, wave = tid >> 6;
  ((int*)h)[tid] = 0;
  __syncthreads();
  const int4* p = (const int4*)(tk_idx + blockIdx.x * 4096);
  #pragma unroll
  for (int i = 0; i < 4; i++){
    int4 v = p[i * 256 + tid];
    atomicAdd(&h[wave][v.x], 1); atomicAdd(&h[wave][v.y], 1);
    atomicAdd(&h[wave][v.z], 1); atomicAdd(&h[wave][v.w], 1);
  }
  __syncthreads();
  if (tid < 64)
    g_hist[blockIdx.x * 64 + tid] = h[0][tid] + h[1][tid] + h[2][tid] + h[3][tid];
}

// ---------------- scan: expert offsets + per-chunk bases ----------------
__global__ void k_scan(const int* __restrict__ g_hist,
                       int* __restrict__ offsets,
                       int* __restrict__ g_base){
  const int e = threadIdx.x;
  int h[CHUNKS]; int tot = 0;
  #pragma unroll
  for (int c = 0; c < CHUNKS; c++){ h[c] = g_hist[c * 64 + e]; tot += h[c]; }
  int inc = tot;
  #pragma unroll
  for (int off = 1; off < 64; off <<= 1){
    int n = __shfl_up(inc, off, 64);
    if (e >= off) inc += n;
  }
  int exc = inc - tot;
  offsets[e] = exc;
  if (e == 63) offsets[64] = inc;
  int b = exc;
  #pragma unroll
  for (int c = 0; c < CHUNKS; c++){ g_base[c * 64 + e] = b; b += h[c]; }
}

// ---------------- scatter: compact slots + inverse map ----------------
__global__ __launch_bounds__(256) void k_scatter(const int* __restrict__ tk_idx,
                                                 const int* __restrict__ g_base,
                                                 int* __restrict__ slot_token,
                                                 int* __restrict__ inv_pos){
  __shared__ int cnt[64];
  const int tid = threadIdx.x;
  if (tid < 64) cnt[tid] = g_base[blockIdx.x * 64 + tid];
  __syncthreads();
  const int base = blockIdx.x * 4096;
  #pragma unroll
  for (int i = 0; i < 16; i++){
    int gid = base + i * 256 + tid;
    int e = tk_idx[gid];
    int pos = atomicAdd(&cnt[e], 1);   // LDS atomic
    slot_token[pos] = gid >> 3;
    inv_pos[gid] = pos;
  }
}

// ============ GEMM1: 256x256 tile, 8-phase counted-vmcnt (R9 verified body) ============
// + R11 all-active bijective XCD grid (512 flat blocks, 8 experts/XCD) + M-loop.
// Staging-round logical-row maps align LDS halves with QUAD quadrants (R8 race fix).
#define QUAD(MH, NH, buf, AS, BS) { \
  bf16x8 qaf[4][2], qbg[2][2]; \
  const int abase_ = ((MH) << 7) + (wm >> 1); \
  const int bbase_ = ((NH) << 7) + (wn >> 1); \
  _Pragma("unroll") for (int i = 0; i < 4; i++) \
    _Pragma("unroll") for (int ks = 0; ks < 2; ks++) \
      qaf[i][ks] = *(const bf16x8*)&AS[buf][((abase_ + (i<<4) + fr) << 6) + ((((ks<<2)+kc)^rxor)<<3)]; \
  _Pragma("unroll") for (int j = 0; j < 2; j++) \
    _Pragma("unroll") for (int ks = 0; ks < 2; ks++) \
      qbg[j][ks] = *(const bf16x8*)&BS[buf][((bbase_ + (j<<4) + fr) << 6) + ((((ks<<2)+kc)^rxor)<<3)]; \
  __builtin_amdgcn_s_setprio(1); \
  _Pragma("unroll") for (int ks = 0; ks < 2; ks++) \
    _Pragma("unroll") for (int i = 0; i < 4; i++) \
      _Pragma("unroll") for (int j = 0; j < 2; j++) \
        acc[((MH)<<2)+i][((NH)<<1)+j] = __builtin_amdgcn_mfma_f32_16x16x32_bf16( \
            qaf[i][ks], qbg[j][ks], acc[((MH)<<2)+i][((NH)<<1)+j], 0, 0, 0); \
  __builtin_amdgcn_s_setprio(0); \
}

__device__ __forceinline__ int lrA_map(int q, int srow){
  return ((q & 1) << 7) + ((q >> 1) << 6) + srow;
}
__device__ __forceinline__ int lrB_map(int q, int srow){
  return ((((q & 1) << 1) | (srow >> 5)) << 6) + ((q >> 1) << 5) + (srow & 31);
}

__global__ __launch_bounds__(512) void k_gemm1(const __bf16* __restrict__ xb,
                                               const __bf16* __restrict__ wupT,  // [E][H][D]
                                               const int* __restrict__ offsets,
                                               const int* __restrict__ slot_token,
                                               __bf16* __restrict__ h){
  const int bid = blockIdx.x;                    // 512 blocks, all active
  const int L   = ((bid & 7) << 6) | (bid >> 3); // XCD k -> experts [8k,8k+8)
  const int e   = L >> 3;
  const int mb  = L & 3;
  const int nb  = (L >> 2) & 1;
  const int base = offsets[e];
  const int ne   = offsets[e + 1] - base;
  const int n0   = nb << 8;

  __shared__ __align__(16) __bf16 As[2][256 * 64];
  __shared__ __align__(16) __bf16 Bs[2][256 * 64];
  __shared__ int s_tok[256];

  const int tid = threadIdx.x;
  const int wave = tid >> 6, lane = tid & 63;
  const int wm = (wave >> 2) << 7;   // 0 or 128
  const int wn = (wave & 3) << 6;    // 0,64,128,192
  const int fr = lane & 15, kc = lane >> 4;
  const int rxor = fr & 7;
  const __bf16* wB = wupT + (size_t)e * HDIM * DDIM + (size_t)n0 * DDIM;

  const int srow = (wave << 3) + (lane >> 3);
  const int scol = (((lane & 7) ^ (lane >> 3)) << 3);   // inverse-swizzled source chunk
  const __bf16* gB[4]; int ldsOff[4];
  #pragma unroll
  for (int q = 0; q < 4; q++){
    gB[q] = wB + (size_t)lrB_map(q, srow) * DDIM + scol;
    ldsOff[q] = (q << 12) + (wave << 9);
  }

  const int cr = (lane >> 4) << 2, cc = lane & 15;

  for (int m0 = mb << 8; m0 < ne; m0 += 1024){
    __syncthreads();
    if (tid < 256){
      int r = m0 + tid;
      s_tok[tid] = slot_token[base + (r < ne ? r : (ne - 1))];
    }
    __syncthreads();

    const __bf16* gA[4];
    #pragma unroll
    for (int q = 0; q < 4; q++)
      gA[q] = xb + (size_t)s_tok[lrA_map(q, srow)] * DDIM + scol;

    f32x4 acc[8][4];
    #pragma unroll
    for (int i=0;i<8;i++)
      #pragma unroll
      for (int j=0;j<4;j++) acc[i][j] = (f32x4){0.f,0.f,0.f,0.f};

    auto stA = [&](int buf, int hf, int koff){
      load_lds16(gA[(hf<<1)]   + koff, (void*)&As[buf][ldsOff[(hf<<1)]]);
      load_lds16(gA[(hf<<1)|1] + koff, (void*)&As[buf][ldsOff[(hf<<1)|1]]);
    };
    auto stB = [&](int buf, int hf, int koff){
      load_lds16(gB[(hf<<1)]   + koff, (void*)&Bs[buf][ldsOff[(hf<<1)]]);
      load_lds16(gB[(hf<<1)|1] + koff, (void*)&Bs[buf][ldsOff[(hf<<1)|1]]);
    };

    // prologue: tile 0's four halves (8 loads in flight)
    stA(0,0,0); stB(0,0,0); stA(0,1,0); stB(0,1,0);

    const int NK = DDIM / 64;
    for (int t = 0; t < NK - 1; ++t){
      const int p = t & 1, pn = p ^ 1;
      const int k1 = (t + 1) << 6;
      stA(pn,0,k1); VM6(); BAR(); SB0(); QUAD(0,0,p,As,Bs);
      stB(pn,0,k1); VM6(); BAR(); SB0(); QUAD(1,0,p,As,Bs);
      stA(pn,1,k1); VM6(); BAR(); SB0(); QUAD(0,1,p,As,Bs);
      stB(pn,1,k1);        BAR(); SB0(); QUAD(1,1,p,As,Bs); BAR();
    }
    { // last tile: drain 4 -> 2 -> 0
      const int p = (NK - 1) & 1;
      VM4(); BAR(); SB0(); QUAD(0,0,p,As,Bs);
      VM2(); BAR(); SB0(); QUAD(1,0,p,As,Bs);
      VM0(); BAR(); SB0(); QUAD(0,1,p,As,Bs);
             BAR(); SB0(); QUAD(1,1,p,As,Bs);
    }

    #pragma unroll
    for (int i=0;i<8;i++){
      #pragma unroll
      for (int reg=0;reg<4;reg++){
        int rl = wm + (i << 4) + cr + reg;
        int gm = m0 + rl;
        if (gm < ne){
          __bf16* hrow = h + (size_t)(base + gm) * HDIM + n0 + wn;
          #pragma unroll
          for (int j=0;j<4;j++){
            float v  = acc[i][j][reg];
            float sv = v / (1.0f + __expf(-v));
            unsigned short u = f2bfbits(sv);
            int part = __shfl_xor((int)u, 1, 64);
            if (!(lane & 1)){
              unsigned int packed = ((unsigned int)(unsigned short)part << 16) | u;
              *(unsigned int*)((unsigned short*)hrow + (j << 4) + cc) = packed;
            }
          }
        }
      }
    }
  }
}

// ---------------- GEMM2: 128x128, BK=64, 4 waves, 66KB LDS, 2 blocks/CU (R14 best) ----------------
__global__ __launch_bounds__(256, 2) void k_gemm2(const __bf16* __restrict__ h,
                                                  const __bf16* __restrict__ wdownT, // [E][D][H]
                                                  const int* __restrict__ offsets,
                                                  __bf16* __restrict__ y,
                                                  int elo){
  const int bid = blockIdx.x;                     // 2048 blocks per 32-expert group
  const int L   = ((bid & 7) << 8) | (bid >> 3);  // XCD k -> 4 whole experts
  const int e   = elo + (L >> 6);
  const int mb  = L & 7;
  const int nb  = (L >> 3) & 7;
  const int base = offsets[e];
  const int ne   = offsets[e + 1] - base;
  const int n0   = nb << 7;
  const int ybase = offsets[elo];

  __shared__ __align__(16) __bf16 As[2][128 * 64];
  __shared__ __align__(16) __bf16 Bs[2][128 * 64];

  const int tid = threadIdx.x;
  const int wave = tid >> 6, lane = tid & 63;
  const int wm = (wave >> 1) << 6;
  const int wn = (wave & 1) << 6;
  const int fr = lane & 15, kc = lane >> 4;
  const int rxor = fr & 7;
  const __bf16* wB = wdownT + (size_t)e * DDIM * HDIM + (size_t)n0 * HDIM;

  const int srl  = lane >> 3;                       // row-in-8
  const int scol = ((lane & 7) ^ srl) << 3;
  const __bf16* gB[4]; int ldsOff[4];
  #pragma unroll
  for (int q = 0; q < 4; q++){
    int r = (wave << 5) + (q << 3) + srl;
    gB[q] = wB + (size_t)r * HDIM + scol;
    ldsOff[q] = ((wave << 5) + (q << 3)) << 6;
  }

  const int cr = (lane >> 4) << 2, cc = lane & 15;

  for (int m0 = mb << 7; m0 < ne; m0 += 1024){
    const __bf16* gA[4];
    #pragma unroll
    for (int q = 0; q < 4; q++){
      int sl = m0 + (wave << 5) + (q << 3) + srl; if (sl >= ne) sl = ne - 1;
      gA[q] = h + (size_t)(base + sl) * HDIM + scol;
    }

    f32x4 acc[4][4];
    #pragma unroll
    for (int i=0;i<4;i++)
      #pragma unroll
      for (int j=0;j<4;j++) acc[i][j] = (f32x4){0.f,0.f,0.f,0.f};

    __syncthreads();
    #pragma unroll
    for (int q = 0; q < 4; q++){
      load_lds16(gA[q], (void*)&As[0][ldsOff[q]]);
      load_lds16(gB[q], (void*)&Bs[0][ldsOff[q]]);
    }
    __syncthreads();

    const int NK = HDIM / 64;
    for (int t = 0; t < NK; ++t){
      const int cur = t & 1;
      if (t + 1 < NK){
        const int k1 = (t + 1) << 6;
        const int nxt = cur ^ 1;
        #pragma unroll
        for (int q = 0; q < 4; q++){
          load_lds16(gA[q] + k1, (void*)&As[nxt][ldsOff[q]]);
          load_lds16(gB[q] + k1, (void*)&Bs[nxt][ldsOff[q]]);
        }
      }
      #pragma unroll
      for (int ks = 0; ks < 2; ks++){
        const int cA = (((ks << 2) + kc) ^ rxor) << 3;
        bf16x8 af[4], bg[4];
        #pragma unroll
        for (int i=0;i<4;i++) af[i] = *(const bf16x8*)&As[cur][((wm + (i<<4) + fr) << 6) + cA];
        #pragma unroll
        for (int j=0;j<4;j++) bg[j] = *(const bf16x8*)&Bs[cur][((wn + (j<<4) + fr) << 6) + cA];
        #pragma unroll
        for (int i=0;i<4;i++)
          #pragma unroll
          for (int j=0;j<4;j++)
            acc[i][j] = __builtin_amdgcn_mfma_f32_16x16x32_bf16(af[i], bg[j], acc[i][j], 0, 0, 0);
      }
      __syncthreads();
    }

    #pragma unroll
    for (int i=0;i<4;i++){
      #pragma unroll
      for (int reg=0;reg<4;reg++){
        int rl = wm + (i << 4) + cr + reg;
        int gm = m0 + rl;
        if (gm < ne){
          __bf16* yrow = y + (size_t)(base - ybase + gm) * DDIM + n0 + wn;
          #pragma unroll
          for (int j=0;j<4;j++){
            unsigned short u = f2bfbits(acc[i][j][reg]);
            int part = __shfl_xor((int)u, 1, 64);
            if (!(lane & 1)){
              unsigned int packed = ((unsigned int)(unsigned short)part << 16) | u;
              *(unsigned int*)((unsigned short*)yrow + (j << 4) + cc) = packed;
            }
          }
        }
      }
    }
  }
}

// ---------------- combine: out[t] (+)= sum_k w_k * y[pos(t,k)] for experts in [elo,ehi) ----------------
__global__ __launch_bounds__(256) void k_combine(const __bf16* __restrict__ y,
                                                 const int* __restrict__ tk_idx,
                                                 const float* __restrict__ tk_w,
                                                 const int* __restrict__ inv_pos,
                                                 const int* __restrict__ offsets,
                                                 float* __restrict__ out,
                                                 int elo, int ehi, int first){
  const int t   = blockIdx.x;
  const int tid = threadIdx.x;
  __shared__ int se[8]; __shared__ float sw[8]; __shared__ int sp[8];
  if (tid < 8){
    se[tid] = tk_idx[(size_t)t * 8 + tid];
    sw[tid] = tk_w [(size_t)t * 8 + tid];
    sp[tid] = inv_pos[(size_t)t * 8 + tid];
  }
  __syncthreads();
  const int ybase = offsets[elo];
  const int c = tid << 2;
  float4 acc;
  if (first) acc = make_float4(0.f, 0.f, 0.f, 0.f);
  else       acc = *(const float4*)&out[(size_t)t * DDIM + c];
  #pragma unroll
  for (int k = 0; k < 8; k++){
    int e = se[k];
    if (e >= elo && e < ehi){
      const unsigned short* yr = (const unsigned short*)y + (size_t)(sp[k] - ybase) * DDIM + c;
      ushort4 raw = *(const ushort4*)yr;
      float w = sw[k];
      acc.x += w * bf2f(raw.x);
      acc.y += w * bf2f(raw.y);
      acc.z += w * bf2f(raw.z);
      acc.w += w * bf2f(raw.w);
    }
  }
  *(float4*)&out[(size_t)t * DDIM + c] = acc;
}

// ---------------- host launch ----------------
extern "C" void kernel_launch(void* const* d_in, const int* in_sizes, int n_in,
                              void* d_out, int out_size, void* d_ws, size_t ws_size,
                              hipStream_t stream){
  const float* x     = (const float*)d_in[0];
  const float* Wg    = (const float*)d_in[1];
  const float* Wup   = (const float*)d_in[2];
  const float* Wdown = (const float*)d_in[3];
  float* out = (float*)d_out;

  char* ws = (char*)d_ws;
  size_t off = 0;
  auto alloc = [&](size_t bytes) -> void* {
    void* p = ws + off;
    off += (bytes + 255) & ~(size_t)255;
    return p;
  };
  // [wupT][xb][logits] are DEAD after k_gemm1; reused as the per-group y buffer.
  __bf16* wupT      = (__bf16*)alloc((size_t)NEXP * DDIM * HDIM * 2);  // 67.1 MB
  __bf16* xb        = (__bf16*)alloc((size_t)T_TOK * DDIM * 2);        // 16.8 MB
  float*  logits    = (float*)alloc((size_t)T_TOK * NEXP * 4);         //  2.1 MB
  __bf16* wdownT    = (__bf16*)alloc((size_t)NEXP * DDIM * HDIM * 2);  // 67.1 MB
  __bf16* hbuf      = (__bf16*)alloc((size_t)T_TOK * TOPK * HDIM * 2); // 67.1 MB
  int*    tk_idx    = (int*)  alloc((size_t)T_TOK * TOPK * 4);
  float*  tk_w      = (float*)alloc((size_t)T_TOK * TOPK * 4);
  int*    slot_tok  = (int*)  alloc((size_t)T_TOK * TOPK * 4);
  int*    inv_pos   = (int*)  alloc((size_t)T_TOK * TOPK * 4);
  int*    g_hist    = (int*)  alloc((size_t)CHUNKS * 64 * 4);
  int*    g_base    = (int*)  alloc((size_t)CHUNKS * 64 * 4);
  int*    offsets   = (int*)  alloc(512);
  __bf16* ybuf      = (__bf16*)ws;   // alias over wupT+xb+logits

  k_gate<<<T_TOK / 64, 256, 0, stream>>>(x, Wg, logits, xb);
  k_transpose_both<<<16384, 256, 0, stream>>>(Wdown, Wup, wdownT, wupT);
  k_topk<<<T_TOK / 4, 256, 0, stream>>>(logits, tk_idx, tk_w);
  k_hist<<<CHUNKS, 256, 0, stream>>>(tk_idx, g_hist);
  k_scan<<<1, 64, 0, stream>>>(g_hist, offsets, g_base);
  k_scatter<<<CHUNKS, 256, 0, stream>>>(tk_idx, g_base, slot_tok, inv_pos);
  // gemm1: 256x256 8-phase counted-vmcnt, all-active XCD grid
  k_gemm1<<<512, 512, 0, stream>>>(xb, wupT, offsets, slot_tok, hbuf);
  // gemm2: 128x128 BK=64, 2 blocks/CU, per 32-expert group
  k_gemm2<<<2048, 256, 0, stream>>>(hbuf, wdownT, offsets, ybuf, 0);
  k_combine<<<T_TOK, 256, 0, stream>>>(ybuf, tk_idx, tk_w, inv_pos, offsets, out, 0, 32, 1);
  k_gemm2<<<2048, 256, 0, stream>>>(hbuf, wdownT, offsets, ybuf, 32);
  k_combine<<<T_TOK, 256, 0, stream>>>(ybuf, tk_idx, tk_w, inv_pos, offsets, out, 32, 64, 0);
}

// Round 23
// 573.226 us; speedup vs baseline: 1.0670x; 1.0670x over previous
//
#include <hip/hip_runtime.h>
#include <hip/hip_bf16.h>
#include <stdint.h>
#include <math.h>

#define T_TOK 8192
#define DDIM  1024
#define HDIM  512
#define NEXP  64
#define TOPK  8
#define CHUNKS 16

typedef __bf16 bf16x8 __attribute__((ext_vector_type(8)));
typedef float  f32x4  __attribute__((ext_vector_type(4)));

__device__ __forceinline__ void load_lds16(const void* gp, void* lp){
  __builtin_amdgcn_global_load_lds(
      (__attribute__((address_space(1))) void*)(uintptr_t)gp,
      (__attribute__((address_space(3))) void*)lp, 16, 0, 0);
}

__device__ __forceinline__ unsigned short f2bfbits(float f){
  union { __bf16 b; unsigned short u; } cv; cv.b = (__bf16)f; return cv.u;
}
__device__ __forceinline__ float bf2f(unsigned short s){
  unsigned int u = ((unsigned int)s) << 16; return __uint_as_float(u);
}

// ------- merged transpose+convert for BOTH weights, 64x64 tiles -------
// blocks [0,8192): Wdown (R=512,C=1024); [8192,16384): Wup (R=1024,C=512).
__global__ __launch_bounds__(256) void k_transpose_both(const float* __restrict__ Wdown,
                                                        const float* __restrict__ Wup,
                                                        __bf16* __restrict__ wdownT,
                                                        __bf16* __restrict__ wupT){
  __shared__ float tile[64][65];
  const int b = blockIdx.x;
  const float* src; __bf16* dst; int R, C, c0, r0, z;
  if (b < 8192){
    z = b >> 7; int tt = b & 127;
    c0 = (tt & 15) << 6; r0 = (tt >> 4) << 6;   // C/64=16, R/64=8
    src = Wdown; dst = wdownT; R = HDIM; C = DDIM;
  } else {
    int bb = b - 8192;
    z = bb >> 7; int tt = bb & 127;
    c0 = (tt & 7) << 6; r0 = (tt >> 3) << 6;    // C/64=8, R/64=16
    src = Wup; dst = wupT; R = DDIM; C = HDIM;
  }
  const float* s = src + (size_t)z * R * C;
  __bf16*      d = dst + (size_t)z * R * C;
  const int t = threadIdx.x;
  const int rrow = t >> 4, rchunk = t & 15;
  #pragma unroll
  for (int rep = 0; rep < 4; rep++){
    int r = rrow + (rep << 4);
    float4 v = *(const float4*)(s + (size_t)(r0 + r) * C + c0 + (rchunk << 2));
    tile[(rchunk << 2) + 0][r] = v.x;
    tile[(rchunk << 2) + 1][r] = v.y;
    tile[(rchunk << 2) + 2][r] = v.z;
    tile[(rchunk << 2) + 3][r] = v.w;
  }
  __syncthreads();
  const int wc = t >> 3, wj = t & 7;
  #pragma unroll
  for (int rep = 0; rep < 2; rep++){
    int c = wc + (rep << 5);
    bf16x8 o;
    #pragma unroll
    for (int sidx = 0; sidx < 8; sidx++)
      o[sidx] = (__bf16)tile[c][(wj << 3) + sidx];
    *(bf16x8*)(d + (size_t)(c0 + c) * R + r0 + (wj << 3)) = o;
  }
}

// ---------------- gate GEMM + fused x->bf16: logits[T][64] (f64 accumulate) ----------------
__global__ __launch_bounds__(256) void k_gate(const float* __restrict__ x,
                                              const float* __restrict__ Wg,
                                              float* __restrict__ logits,
                                              __bf16* __restrict__ xb){
  __shared__ float xs[32][64];
  __shared__ float ws[32][64];
  const int tid = threadIdx.x;
  const int m0  = blockIdx.x * 64;
  const int tm  = (tid >> 4) << 2;
  const int tn  = (tid & 15) << 2;
  const int sr  = tid >> 2;
  const int sc  = tid & 3;
  double acc[4][4];
  #pragma unroll
  for (int i=0;i<4;i++)
    #pragma unroll
    for (int j=0;j<4;j++) acc[i][j]=0.0;

  for (int k0 = 0; k0 < DDIM; k0 += 32){
    {
      const float4* g = (const float4*)(Wg + (size_t)k0 * 64);
      float4* l = (float4*)&ws[0][0];
      l[tid]       = g[tid];
      l[tid + 256] = g[tid + 256];
    }
    {
      const float* g = x + (size_t)(m0 + sr) * DDIM + k0 + sc * 8;
      float4 a = *(const float4*)g;
      float4 b = *(const float4*)(g + 4);
      xs[sc*8+0][sr]=a.x; xs[sc*8+1][sr]=a.y; xs[sc*8+2][sr]=a.z; xs[sc*8+3][sr]=a.w;
      xs[sc*8+4][sr]=b.x; xs[sc*8+5][sr]=b.y; xs[sc*8+6][sr]=b.z; xs[sc*8+7][sr]=b.w;
      bf16x8 o;
      o[0]=(__bf16)a.x; o[1]=(__bf16)a.y; o[2]=(__bf16)a.z; o[3]=(__bf16)a.w;
      o[4]=(__bf16)b.x; o[5]=(__bf16)b.y; o[6]=(__bf16)b.z; o[7]=(__bf16)b.w;
      *(bf16x8*)(xb + (size_t)(m0 + sr) * DDIM + k0 + sc * 8) = o;
    }
    __syncthreads();
    for (int k = 0; k < 32; k++){
      float4 a4 = *(const float4*)&xs[k][tm];
      float4 b4 = *(const float4*)&ws[k][tn];
      float av[4] = {a4.x,a4.y,a4.z,a4.w};
      float bv[4] = {b4.x,b4.y,b4.z,b4.w};
      #pragma unroll
      for (int i=0;i<4;i++)
        #pragma unroll
        for (int j=0;j<4;j++)
          acc[i][j] += (double)av[i] * (double)bv[j];
    }
    __syncthreads();
  }
  #pragma unroll
  for (int i=0;i<4;i++){
    float4 o = make_float4((float)acc[i][0],(float)acc[i][1],(float)acc[i][2],(float)acc[i][3]);
    *(float4*)&logits[(size_t)(m0 + tm + i) * 64 + tn] = o;
  }
}

// ---------------- top-8 + softmax (wave per token) ----------------
__global__ __launch_bounds__(256) void k_topk(const float* __restrict__ logits,
                                              int* __restrict__ tk_idx,
                                              float* __restrict__ tk_w){
  const int lane = threadIdx.x & 63;
  const int t    = blockIdx.x * 4 + (threadIdx.x >> 6);
  float v = logits[(size_t)t * 64 + lane];
  const int myi = lane;
  float mv[8]; int mi[8];
  #pragma unroll
  for (int k = 0; k < 8; k++){
    float bv = v; int bi = myi;
    #pragma unroll
    for (int off = 32; off > 0; off >>= 1){
      float ov = __shfl_xor(bv, off, 64);
      int   oi = __shfl_xor(bi, off, 64);
      if (ov > bv || (ov == bv && oi < bi)){ bv = ov; bi = oi; }
    }
    mv[k] = bv; mi[k] = bi;
    if (bi == myi) v = -INFINITY;
  }
  float w[8]; float s = 0.f;
  #pragma unroll
  for (int k = 0; k < 8; k++){ w[k] = expf(mv[k] - mv[0]); s += w[k]; }
  float inv = 1.0f / s;
  if (lane == 0){
    #pragma unroll
    for (int k = 0; k < 8; k++){
      tk_idx[(size_t)t * 8 + k] = mi[k];
      tk_w [(size_t)t * 8 + k] = w[k] * inv;
    }
  }
}

// ---------------- per-chunk histogram ----------------
__global__ __launch_bounds__(256) void k_hist(const int* __restrict__ tk_idx,
                                              int* __restrict__ g_hist){
  __shared__ int h[4][64];
  const int tid = threadIdx.x, wave = tid >> 6;
  ((int*)h)[tid] = 0;
  __syncthreads();
  const int4* p = (const int4*)(tk_idx + blockIdx.x * 4096);
  #pragma unroll
  for (int i = 0; i < 4; i++){
    int4 v = p[i * 256 + tid];
    atomicAdd(&h[wave][v.x], 1); atomicAdd(&h[wave][v.y], 1);
    atomicAdd(&h[wave][v.z], 1); atomicAdd(&h[wave][v.w], 1);
  }
  __syncthreads();
  if (tid < 64)
    g_hist[blockIdx.x * 64 + tid] = h[0][tid] + h[1][tid] + h[2][tid] + h[3][tid];
}

// ---------------- scan: expert offsets + per-chunk bases ----------------
__global__ void k_scan(const int* __restrict__ g_hist,
                       int* __restrict__ offsets,
                       int* __restrict__ g_base){
  const int e = threadIdx.x;
  int h[CHUNKS]; int tot = 0;
  #pragma unroll
  for (int c = 0; c < CHUNKS; c++){ h[c] = g_hist[c * 64 + e]; tot += h[c]; }
  int inc = tot;
  #pragma unroll
  for (int off = 1; off < 64; off <<= 1){
    int n = __shfl_up(inc, off, 64);
    if (e >= off) inc += n;
  }
  int exc = inc - tot;
  offsets[e] = exc;
  if (e == 63) offsets[64] = inc;
  int b = exc;
  #pragma unroll
  for (int c = 0; c < CHUNKS; c++){ g_base[c * 64 + e] = b; b += h[c]; }
}

// ---------------- scatter: compact slots + inverse map ----------------
__global__ __launch_bounds__(256) void k_scatter(const int* __restrict__ tk_idx,
                                                 const int* __restrict__ g_base,
                                                 int* __restrict__ slot_token,
                                                 int* __restrict__ inv_pos){
  __shared__ int cnt[64];
  const int tid = threadIdx.x;
  if (tid < 64) cnt[tid] = g_base[blockIdx.x * 64 + tid];
  __syncthreads();
  const int base = blockIdx.x * 4096;
  #pragma unroll
  for (int i = 0; i < 16; i++){
    int gid = base + i * 256 + tid;
    int e = tk_idx[gid];
    int pos = atomicAdd(&cnt[e], 1);   // LDS atomic
    slot_token[pos] = gid >> 3;
    inv_pos[gid] = pos;
  }
}

// ---------------- GEMM1: 128x128, BK=32, 4 waves, 32KB LDS, 4 blocks/CU (R12 best) ----------------
__global__ __launch_bounds__(256, 4) void k_gemm1(const __bf16* __restrict__ xb,
                                                  const __bf16* __restrict__ wupT,  // [E][H][D]
                                                  const int* __restrict__ offsets,
                                                  const int* __restrict__ slot_token,
                                                  __bf16* __restrict__ h){
  const int bid = blockIdx.x;                     // 2048 blocks
  const int L   = ((bid & 7) << 8) | (bid >> 3);  // XCD k -> experts [8k, 8k+8)
  const int e   = L >> 5;
  const int mb  = L & 7;
  const int nb  = (L >> 3) & 3;
  const int base = offsets[e];
  const int ne   = offsets[e + 1] - base;
  const int n0   = nb << 7;

  __shared__ __align__(16) __bf16 As[2][128 * 32];
  __shared__ __align__(16) __bf16 Bs[2][128 * 32];
  __shared__ int s_tok[128];

  const int tid = threadIdx.x;
  const int wave = tid >> 6, lane = tid & 63;
  const int wm = (wave >> 1) << 6;
  const int wn = (wave & 1) << 6;
  const int fr = lane & 15, kc = lane >> 4;
  const int rxor = (fr & 3) ^ ((fr >> 2) & 3);
  const __bf16* wB = wupT + (size_t)e * HDIM * DDIM + (size_t)n0 * DDIM;

  const int srl  = lane >> 2;
  const int sxor = (srl & 3) ^ ((srl >> 2) & 3);
  const int scol = ((lane & 3) ^ sxor) << 3;
  const __bf16* gB[2]; int ldsOff[2];
  #pragma unroll
  for (int q = 0; q < 2; q++){
    int r = (q << 6) + (wave << 4) + srl;
    gB[q] = wB + (size_t)r * DDIM + scol;
    ldsOff[q] = (q << 11) + (wave << 9);
  }

  const int cr = (lane >> 4) << 2, cc = lane & 15;

  for (int m0 = mb << 7; m0 < ne; m0 += 1024){
    __syncthreads();
    if (tid < 128){
      int r = m0 + tid;
      s_tok[tid] = slot_token[base + (r < ne ? r : (ne - 1))];
    }
    __syncthreads();

    const __bf16* gA[2];
    #pragma unroll
    for (int q = 0; q < 2; q++)
      gA[q] = xb + (size_t)s_tok[(q << 6) + (wave << 4) + srl] * DDIM + scol;

    f32x4 acc[4][4];
    #pragma unroll
    for (int i=0;i<4;i++)
      #pragma unroll
      for (int j=0;j<4;j++) acc[i][j] = (f32x4){0.f,0.f,0.f,0.f};

    #pragma unroll
    for (int q = 0; q < 2; q++){
      load_lds16(gA[q], (void*)&As[0][ldsOff[q]]);
      load_lds16(gB[q], (void*)&Bs[0][ldsOff[q]]);
    }
    __syncthreads();

    const int NK = DDIM / 32;
    for (int t = 0; t < NK; ++t){
      const int cur = t & 1;
      if (t + 1 < NK){
        const int k1 = (t + 1) << 5;
        const int nxt = cur ^ 1;
        #pragma unroll
        for (int q = 0; q < 2; q++){
          load_lds16(gA[q] + k1, (void*)&As[nxt][ldsOff[q]]);
          load_lds16(gB[q] + k1, (void*)&Bs[nxt][ldsOff[q]]);
        }
      }
      const int cA = (kc ^ rxor) << 3;
      bf16x8 af[4], bg[4];
      #pragma unroll
      for (int i=0;i<4;i++) af[i] = *(const bf16x8*)&As[cur][((wm + (i<<4) + fr) << 5) + cA];
      #pragma unroll
      for (int j=0;j<4;j++) bg[j] = *(const bf16x8*)&Bs[cur][((wn + (j<<4) + fr) << 5) + cA];
      #pragma unroll
      for (int i=0;i<4;i++)
        #pragma unroll
        for (int j=0;j<4;j++)
          acc[i][j] = __builtin_amdgcn_mfma_f32_16x16x32_bf16(af[i], bg[j], acc[i][j], 0, 0, 0);
      __syncthreads();
    }

    #pragma unroll
    for (int i=0;i<4;i++){
      #pragma unroll
      for (int reg=0;reg<4;reg++){
        int rl = wm + (i << 4) + cr + reg;
        int gm = m0 + rl;
        if (gm < ne){
          __bf16* hrow = h + (size_t)(base + gm) * HDIM + n0 + wn;
          #pragma unroll
          for (int j=0;j<4;j++){
            float v  = acc[i][j][reg];
            float sv = v / (1.0f + __expf(-v));
            unsigned short u = f2bfbits(sv);
            int part = __shfl_xor((int)u, 1, 64);
            if (!(lane & 1)){
              unsigned int packed = ((unsigned int)(unsigned short)part << 16) | u;
              *(unsigned int*)((unsigned short*)hrow + (j << 4) + cc) = packed;
            }
          }
        }
      }
    }
  }
}

// ---------------- GEMM2: 128x128, BK=64, 4 waves, 66KB LDS, 2 blocks/CU (R14 best) ----------------
__global__ __launch_bounds__(256, 2) void k_gemm2(const __bf16* __restrict__ h,
                                                  const __bf16* __restrict__ wdownT, // [E][D][H]
                                                  const int* __restrict__ offsets,
                                                  __bf16* __restrict__ y,
                                                  int elo){
  const int bid = blockIdx.x;                     // 2048 blocks per 32-expert group
  const int L   = ((bid & 7) << 8) | (bid >> 3);  // XCD k -> 4 whole experts
  const int e   = elo + (L >> 6);
  const int mb  = L & 7;
  const int nb  = (L >> 3) & 7;
  const int base = offsets[e];
  const int ne   = offsets[e + 1] - base;
  const int n0   = nb << 7;
  const int ybase = offsets[elo];

  __shared__ __align__(16) __bf16 As[2][128 * 64];
  __shared__ __align__(16) __bf16 Bs[2][128 * 64];

  const int tid = threadIdx.x;
  const int wave = tid >> 6, lane = tid & 63;
  const int wm = (wave >> 1) << 6;
  const int wn = (wave & 1) << 6;
  const int fr = lane & 15, kc = lane >> 4;
  const int rxor = fr & 7;
  const __bf16* wB = wdownT + (size_t)e * DDIM * HDIM + (size_t)n0 * HDIM;

  const int srl  = lane >> 3;                       // row-in-8
  const int scol = ((lane & 7) ^ srl) << 3;
  const __bf16* gB[4]; int ldsOff[4];
  #pragma unroll
  for (int q = 0; q < 4; q++){
    int r = (wave << 5) + (q << 3) + srl;
    gB[q] = wB + (size_t)r * HDIM + scol;
    ldsOff[q] = ((wave << 5) + (q << 3)) << 6;
  }

  const int cr = (lane >> 4) << 2, cc = lane & 15;

  for (int m0 = mb << 7; m0 < ne; m0 += 1024){
    const __bf16* gA[4];
    #pragma unroll
    for (int q = 0; q < 4; q++){
      int sl = m0 + (wave << 5) + (q << 3) + srl; if (sl >= ne) sl = ne - 1;
      gA[q] = h + (size_t)(base + sl) * HDIM + scol;
    }

    f32x4 acc[4][4];
    #pragma unroll
    for (int i=0;i<4;i++)
      #pragma unroll
      for (int j=0;j<4;j++) acc[i][j] = (f32x4){0.f,0.f,0.f,0.f};

    __syncthreads();
    #pragma unroll
    for (int q = 0; q < 4; q++){
      load_lds16(gA[q], (void*)&As[0][ldsOff[q]]);
      load_lds16(gB[q], (void*)&Bs[0][ldsOff[q]]);
    }
    __syncthreads();

    const int NK = HDIM / 64;
    for (int t = 0; t < NK; ++t){
      const int cur = t & 1;
      if (t + 1 < NK){
        const int k1 = (t + 1) << 6;
        const int nxt = cur ^ 1;
        #pragma unroll
        for (int q = 0; q < 4; q++){
          load_lds16(gA[q] + k1, (void*)&As[nxt][ldsOff[q]]);
          load_lds16(gB[q] + k1, (void*)&Bs[nxt][ldsOff[q]]);
        }
      }
      #pragma unroll
      for (int ks = 0; ks < 2; ks++){
        const int cA = (((ks << 2) + kc) ^ rxor) << 3;
        bf16x8 af[4], bg[4];
        #pragma unroll
        for (int i=0;i<4;i++) af[i] = *(const bf16x8*)&As[cur][((wm + (i<<4) + fr) << 6) + cA];
        #pragma unroll
        for (int j=0;j<4;j++) bg[j] = *(const bf16x8*)&Bs[cur][((wn + (j<<4) + fr) << 6) + cA];
        #pragma unroll
        for (int i=0;i<4;i++)
          #pragma unroll
          for (int j=0;j<4;j++)
            acc[i][j] = __builtin_amdgcn_mfma_f32_16x16x32_bf16(af[i], bg[j], acc[i][j], 0, 0, 0);
      }
      __syncthreads();
    }

    #pragma unroll
    for (int i=0;i<4;i++){
      #pragma unroll
      for (int reg=0;reg<4;reg++){
        int rl = wm + (i << 4) + cr + reg;
        int gm = m0 + rl;
        if (gm < ne){
          __bf16* yrow = y + (size_t)(base - ybase + gm) * DDIM + n0 + wn;
          #pragma unroll
          for (int j=0;j<4;j++){
            unsigned short u = f2bfbits(acc[i][j][reg]);
            int part = __shfl_xor((int)u, 1, 64);
            if (!(lane & 1)){
              unsigned int packed = ((unsigned int)(unsigned short)part << 16) | u;
              *(unsigned int*)((unsigned short*)yrow + (j << 4) + cc) = packed;
            }
          }
        }
      }
    }
  }
}

// ---------------- combine: out[t] (+)= sum_k w_k * y[pos(t,k)] for experts in [elo,ehi) ----------------
__global__ __launch_bounds__(256) void k_combine(const __bf16* __restrict__ y,
                                                 const int* __restrict__ tk_idx,
                                                 const float* __restrict__ tk_w,
                                                 const int* __restrict__ inv_pos,
                                                 const int* __restrict__ offsets,
                                                 float* __restrict__ out,
                                                 int elo, int ehi, int first){
  const int t   = blockIdx.x;
  const int tid = threadIdx.x;
  __shared__ int se[8]; __shared__ float sw[8]; __shared__ int sp[8];
  if (tid < 8){
    se[tid] = tk_idx[(size_t)t * 8 + tid];
    sw[tid] = tk_w [(size_t)t * 8 + tid];
    sp[tid] = inv_pos[(size_t)t * 8 + tid];
  }
  __syncthreads();
  const int ybase = offsets[elo];
  const int c = tid << 2;
  float4 acc;
  if (first) acc = make_float4(0.f, 0.f, 0.f, 0.f);
  else       acc = *(const float4*)&out[(size_t)t * DDIM + c];
  #pragma unroll
  for (int k = 0; k < 8; k++){
    int e = se[k];
    if (e >= elo && e < ehi){
      const unsigned short* yr = (const unsigned short*)y + (size_t)(sp[k] - ybase) * DDIM + c;
      ushort4 raw = *(const ushort4*)yr;
      float w = sw[k];
      acc.x += w * bf2f(raw.x);
      acc.y += w * bf2f(raw.y);
      acc.z += w * bf2f(raw.z);
      acc.w += w * bf2f(raw.w);
    }
  }
  *(float4*)&out[(size_t)t * DDIM + c] = acc;
}

// ---------------- host launch ----------------
extern "C" void kernel_launch(void* const* d_in, const int* in_sizes, int n_in,
                              void* d_out, int out_size, void* d_ws, size_t ws_size,
                              hipStream_t stream){
  const float* x     = (const float*)d_in[0];
  const float* Wg    = (const float*)d_in[1];
  const float* Wup   = (const float*)d_in[2];
  const float* Wdown = (const float*)d_in[3];
  float* out = (float*)d_out;

  char* ws = (char*)d_ws;
  size_t off = 0;
  auto alloc = [&](size_t bytes) -> void* {
    void* p = ws + off;
    off += (bytes + 255) & ~(size_t)255;
    return p;
  };
  // [wupT][xb][logits] are DEAD after k_gemm1; reused as the per-group y buffer.
  __bf16* wupT      = (__bf16*)alloc((size_t)NEXP * DDIM * HDIM * 2);  // 67.1 MB
  __bf16* xb        = (__bf16*)alloc((size_t)T_TOK * DDIM * 2);        // 16.8 MB
  float*  logits    = (float*)alloc((size_t)T_TOK * NEXP * 4);         //  2.1 MB
  __bf16* wdownT    = (__bf16*)alloc((size_t)NEXP * DDIM * HDIM * 2);  // 67.1 MB
  __bf16* hbuf      = (__bf16*)alloc((size_t)T_TOK * TOPK * HDIM * 2); // 67.1 MB
  int*    tk_idx    = (int*)  alloc((size_t)T_TOK * TOPK * 4);
  float*  tk_w      = (float*)alloc((size_t)T_TOK * TOPK * 4);
  int*    slot_tok  = (int*)  alloc((size_t)T_TOK * TOPK * 4);
  int*    inv_pos   = (int*)  alloc((size_t)T_TOK * TOPK * 4);
  int*    g_hist    = (int*)  alloc((size_t)CHUNKS * 64 * 4);
  int*    g_base    = (int*)  alloc((size_t)CHUNKS * 64 * 4);
  int*    offsets   = (int*)  alloc(512);
  __bf16* ybuf      = (__bf16*)ws;   // alias over wupT+xb+logits

  k_gate<<<T_TOK / 64, 256, 0, stream>>>(x, Wg, logits, xb);
  k_transpose_both<<<16384, 256, 0, stream>>>(Wdown, Wup, wdownT, wupT);
  k_topk<<<T_TOK / 4, 256, 0, stream>>>(logits, tk_idx, tk_w);
  k_hist<<<CHUNKS, 256, 0, stream>>>(tk_idx, g_hist);
  k_scan<<<1, 64, 0, stream>>>(g_hist, offsets, g_base);
  k_scatter<<<CHUNKS, 256, 0, stream>>>(tk_idx, g_base, slot_tok, inv_pos);
  // gemm1: 128x128 BK=32, 4 blocks/CU (R12 measured best)
  k_gemm1<<<2048, 256, 0, stream>>>(xb, wupT, offsets, slot_tok, hbuf);
  // gemm2: 128x128 BK=64, 2 blocks/CU, per 32-expert group
  k_gemm2<<<2048, 256, 0, stream>>>(hbuf, wdownT, offsets, ybuf, 0);
  k_combine<<<T_TOK, 256, 0, stream>>>(ybuf, tk_idx, tk_w, inv_pos, offsets, out, 0, 32, 1);
  k_gemm2<<<2048, 256, 0, stream>>>(hbuf, wdownT, offsets, ybuf, 32);
  k_combine<<<T_TOK, 256, 0, stream>>>(ybuf, tk_idx, tk_w, inv_pos, offsets, out, 32, 64, 0);
}

// Round 24
// 573.051 us; speedup vs baseline: 1.0673x; 1.0003x over previous
//
#include <hip/hip_runtime.h>
#include <hip/hip_bf16.h>
#include <stdint.h>
#include <math.h>

#define T_TOK 8192
#define DDIM  1024
#define HDIM  512
#define NEXP  64
#define TOPK  8
#define CHUNKS 16

typedef __bf16 bf16x8 __attribute__((ext_vector_type(8)));
typedef float  f32x4  __attribute__((ext_vector_type(4)));

__device__ __forceinline__ void load_lds16(const void* gp, void* lp){
  __builtin_amdgcn_global_load_lds(
      (__attribute__((address_space(1))) void*)(uintptr_t)gp,
      (__attribute__((address_space(3))) void*)lp, 16, 0, 0);
}

__device__ __forceinline__ unsigned short f2bfbits(float f){
  union { __bf16 b; unsigned short u; } cv; cv.b = (__bf16)f; return cv.u;
}
__device__ __forceinline__ float bf2f(unsigned short s){
  unsigned int u = ((unsigned int)s) << 16; return __uint_as_float(u);
}

// counted waits ("memory" clobber orders all memory ops incl. LDS reads/gload_lds)
#define VM4() asm volatile("s_waitcnt vmcnt(4)" ::: "memory")
#define VM0() asm volatile("s_waitcnt vmcnt(0)" ::: "memory")
#define BAR() __builtin_amdgcn_s_barrier()
#define SB0() __builtin_amdgcn_sched_barrier(0)

// ------- merged transpose+convert for BOTH weights, 64x64 tiles -------
__global__ __launch_bounds__(256) void k_transpose_both(const float* __restrict__ Wdown,
                                                        const float* __restrict__ Wup,
                                                        __bf16* __restrict__ wdownT,
                                                        __bf16* __restrict__ wupT){
  __shared__ float tile[64][65];
  const int b = blockIdx.x;
  const float* src; __bf16* dst; int R, C, c0, r0, z;
  if (b < 8192){
    z = b >> 7; int tt = b & 127;
    c0 = (tt & 15) << 6; r0 = (tt >> 4) << 6;
    src = Wdown; dst = wdownT; R = HDIM; C = DDIM;
  } else {
    int bb = b - 8192;
    z = bb >> 7; int tt = bb & 127;
    c0 = (tt & 7) << 6; r0 = (tt >> 3) << 6;
    src = Wup; dst = wupT; R = DDIM; C = HDIM;
  }
  const float* s = src + (size_t)z * R * C;
  __bf16*      d = dst + (size_t)z * R * C;
  const int t = threadIdx.x;
  const int rrow = t >> 4, rchunk = t & 15;
  #pragma unroll
  for (int rep = 0; rep < 4; rep++){
    int r = rrow + (rep << 4);
    float4 v = *(const float4*)(s + (size_t)(r0 + r) * C + c0 + (rchunk << 2));
    tile[(rchunk << 2) + 0][r] = v.x;
    tile[(rchunk << 2) + 1][r] = v.y;
    tile[(rchunk << 2) + 2][r] = v.z;
    tile[(rchunk << 2) + 3][r] = v.w;
  }
  __syncthreads();
  const int wc = t >> 3, wj = t & 7;
  #pragma unroll
  for (int rep = 0; rep < 2; rep++){
    int c = wc + (rep << 5);
    bf16x8 o;
    #pragma unroll
    for (int sidx = 0; sidx < 8; sidx++)
      o[sidx] = (__bf16)tile[c][(wj << 3) + sidx];
    *(bf16x8*)(d + (size_t)(c0 + c) * R + r0 + (wj << 3)) = o;
  }
}

// ---------------- gate GEMM + fused x->bf16 ----------------
__global__ __launch_bounds__(256) void k_gate(const float* __restrict__ x,
                                              const float* __restrict__ Wg,
                                              float* __restrict__ logits,
                                              __bf16* __restrict__ xb){
  __shared__ float xs[32][64];
  __shared__ float ws[32][64];
  const int tid = threadIdx.x;
  const int m0  = blockIdx.x * 64;
  const int tm  = (tid >> 4) << 2;
  const int tn  = (tid & 15) << 2;
  const int sr  = tid >> 2;
  const int sc  = tid & 3;
  double acc[4][4];
  #pragma unroll
  for (int i=0;i<4;i++)
    #pragma unroll
    for (int j=0;j<4;j++) acc[i][j]=0.0;

  for (int k0 = 0; k0 < DDIM; k0 += 32){
    {
      const float4* g = (const float4*)(Wg + (size_t)k0 * 64);
      float4* l = (float4*)&ws[0][0];
      l[tid]       = g[tid];
      l[tid + 256] = g[tid + 256];
    }
    {
      const float* g = x + (size_t)(m0 + sr) * DDIM + k0 + sc * 8;
      float4 a = *(const float4*)g;
      float4 b = *(const float4*)(g + 4);
      xs[sc*8+0][sr]=a.x; xs[sc*8+1][sr]=a.y; xs[sc*8+2][sr]=a.z; xs[sc*8+3][sr]=a.w;
      xs[sc*8+4][sr]=b.x; xs[sc*8+5][sr]=b.y; xs[sc*8+6][sr]=b.z; xs[sc*8+7][sr]=b.w;
      bf16x8 o;
      o[0]=(__bf16)a.x; o[1]=(__bf16)a.y; o[2]=(__bf16)a.z; o[3]=(__bf16)a.w;
      o[4]=(__bf16)b.x; o[5]=(__bf16)b.y; o[6]=(__bf16)b.z; o[7]=(__bf16)b.w;
      *(bf16x8*)(xb + (size_t)(m0 + sr) * DDIM + k0 + sc * 8) = o;
    }
    __syncthreads();
    for (int k = 0; k < 32; k++){
      float4 a4 = *(const float4*)&xs[k][tm];
      float4 b4 = *(const float4*)&ws[k][tn];
      float av[4] = {a4.x,a4.y,a4.z,a4.w};
      float bv[4] = {b4.x,b4.y,b4.z,b4.w};
      #pragma unroll
      for (int i=0;i<4;i++)
        #pragma unroll
        for (int j=0;j<4;j++)
          acc[i][j] += (double)av[i] * (double)bv[j];
    }
    __syncthreads();
  }
  #pragma unroll
  for (int i=0;i<4;i++){
    float4 o = make_float4((float)acc[i][0],(float)acc[i][1],(float)acc[i][2],(float)acc[i][3]);
    *(float4*)&logits[(size_t)(m0 + tm + i) * 64 + tn] = o;
  }
}

// ---------------- top-8 + softmax (wave per token) ----------------
__global__ __launch_bounds__(256) void k_topk(const float* __restrict__ logits,
                                              int* __restrict__ tk_idx,
                                              float* __restrict__ tk_w){
  const int lane = threadIdx.x & 63;
  const int t    = blockIdx.x * 4 + (threadIdx.x >> 6);
  float v = logits[(size_t)t * 64 + lane];
  const int myi = lane;
  float mv[8]; int mi[8];
  #pragma unroll
  for (int k = 0; k < 8; k++){
    float bv = v; int bi = myi;
    #pragma unroll
    for (int off = 32; off > 0; off >>= 1){
      float ov = __shfl_xor(bv, off, 64);
      int   oi = __shfl_xor(bi, off, 64);
      if (ov > bv || (ov == bv && oi < bi)){ bv = ov; bi = oi; }
    }
    mv[k] = bv; mi[k] = bi;
    if (bi == myi) v = -INFINITY;
  }
  float w[8]; float s = 0.f;
  #pragma unroll
  for (int k = 0; k < 8; k++){ w[k] = expf(mv[k] - mv[0]); s += w[k]; }
  float inv = 1.0f / s;
  if (lane == 0){
    #pragma unroll
    for (int k = 0; k < 8; k++){
      tk_idx[(size_t)t * 8 + k] = mi[k];
      tk_w [(size_t)t * 8 + k] = w[k] * inv;
    }
  }
}

// ---------------- per-chunk histogram ----------------
__global__ __launch_bounds__(256) void k_hist(const int* __restrict__ tk_idx,
                                              int* __restrict__ g_hist){
  __shared__ int h[4][64];
  const int tid = threadIdx.x, wave = tid >> 6;
  ((int*)h)[tid] = 0;
  __syncthreads();
  const int4* p = (const int4*)(tk_idx + blockIdx.x * 4096);
  #pragma unroll
  for (int i = 0; i < 4; i++){
    int4 v = p[i * 256 + tid];
    atomicAdd(&h[wave][v.x], 1); atomicAdd(&h[wave][v.y], 1);
    atomicAdd(&h[wave][v.z], 1); atomicAdd(&h[wave][v.w], 1);
  }
  __syncthreads();
  if (tid < 64)
    g_hist[blockIdx.x * 64 + tid] = h[0][tid] + h[1][tid] + h[2][tid] + h[3][tid];
}

// ---------------- scan: expert offsets + per-chunk bases ----------------
__global__ void k_scan(const int* __restrict__ g_hist,
                       int* __restrict__ offsets,
                       int* __restrict__ g_base){
  const int e = threadIdx.x;
  int h[CHUNKS]; int tot = 0;
  #pragma unroll
  for (int c = 0; c < CHUNKS; c++){ h[c] = g_hist[c * 64 + e]; tot += h[c]; }
  int inc = tot;
  #pragma unroll
  for (int off = 1; off < 64; off <<= 1){
    int n = __shfl_up(inc, off, 64);
    if (e >= off) inc += n;
  }
  int exc = inc - tot;
  offsets[e] = exc;
  if (e == 63) offsets[64] = inc;
  int b = exc;
  #pragma unroll
  for (int c = 0; c < CHUNKS; c++){ g_base[c * 64 + e] = b; b += h[c]; }
}

// ---------------- scatter: compact slots + inverse map ----------------
__global__ __launch_bounds__(256) void k_scatter(const int* __restrict__ tk_idx,
                                                 const int* __restrict__ g_base,
                                                 int* __restrict__ slot_token,
                                                 int* __restrict__ inv_pos){
  __shared__ int cnt[64];
  const int tid = threadIdx.x;
  if (tid < 64) cnt[tid] = g_base[blockIdx.x * 64 + tid];
  __syncthreads();
  const int base = blockIdx.x * 4096;
  #pragma unroll
  for (int i = 0; i < 16; i++){
    int gid = base + i * 256 + tid;
    int e = tk_idx[gid];
    int pos = atomicAdd(&cnt[e], 1);   // LDS atomic
    slot_token[pos] = gid >> 3;
    inv_pos[gid] = pos;
  }
}

// ---------------- GEMM1: 128x128, BK=32, 4 waves, 4 blocks/CU + COUNTED vmcnt (T4) ----------------
// R12 tiling; raw s_barrier + VM4 lets tile-t+1's 4 gload_lds stay in flight across
// tile-t's MFMA phase (no per-step drain-to-0). FIFO-verified: VM4 retires exactly
// the current tile's loads; trailing BAR + SB0 protects the WAR on buffer reuse.
__global__ __launch_bounds__(256, 4) void k_gemm1(const __bf16* __restrict__ xb,
                                                  const __bf16* __restrict__ wupT,  // [E][H][D]
                                                  const int* __restrict__ offsets,
                                                  const int* __restrict__ slot_token,
                                                  __bf16* __restrict__ h){
  const int bid = blockIdx.x;                     // 2048 blocks
  const int L   = ((bid & 7) << 8) | (bid >> 3);  // XCD k -> experts [8k, 8k+8)
  const int e   = L >> 5;
  const int mb  = L & 7;
  const int nb  = (L >> 3) & 3;
  const int base = offsets[e];
  const int ne   = offsets[e + 1] - base;
  const int n0   = nb << 7;

  __shared__ __align__(16) __bf16 As[2][128 * 32];
  __shared__ __align__(16) __bf16 Bs[2][128 * 32];
  __shared__ int s_tok[128];

  const int tid = threadIdx.x;
  const int wave = tid >> 6, lane = tid & 63;
  const int wm = (wave >> 1) << 6;
  const int wn = (wave & 1) << 6;
  const int fr = lane & 15, kc = lane >> 4;
  const int rxor = (fr & 3) ^ ((fr >> 2) & 3);
  const __bf16* wB = wupT + (size_t)e * HDIM * DDIM + (size_t)n0 * DDIM;

  const int srl  = lane >> 2;
  const int sxor = (srl & 3) ^ ((srl >> 2) & 3);
  const int scol = ((lane & 3) ^ sxor) << 3;
  const __bf16* gB[2]; int ldsOff[2];
  #pragma unroll
  for (int q = 0; q < 2; q++){
    int r = (q << 6) + (wave << 4) + srl;
    gB[q] = wB + (size_t)r * DDIM + scol;
    ldsOff[q] = (q << 11) + (wave << 9);
  }

  const int cr = (lane >> 4) << 2, cc = lane & 15;

  for (int m0 = mb << 7; m0 < ne; m0 += 1024){
    __syncthreads();
    if (tid < 128){
      int r = m0 + tid;
      s_tok[tid] = slot_token[base + (r < ne ? r : (ne - 1))];
    }
    __syncthreads();

    const __bf16* gA[2];
    #pragma unroll
    for (int q = 0; q < 2; q++)
      gA[q] = xb + (size_t)s_tok[(q << 6) + (wave << 4) + srl] * DDIM + scol;

    f32x4 acc[4][4];
    #pragma unroll
    for (int i=0;i<4;i++)
      #pragma unroll
      for (int j=0;j<4;j++) acc[i][j] = (f32x4){0.f,0.f,0.f,0.f};

    // prologue: tile 0 into buffer 0, full drain once
    #pragma unroll
    for (int q = 0; q < 2; q++){
      load_lds16(gA[q], (void*)&As[0][ldsOff[q]]);
      load_lds16(gB[q], (void*)&Bs[0][ldsOff[q]]);
    }
    VM0(); BAR(); SB0();

    const int NK = DDIM / 32;
    for (int t = 0; t < NK; ++t){
      const int cur = t & 1;
      if (t + 1 < NK){
        const int k1 = (t + 1) << 5;
        const int nxt = cur ^ 1;
        #pragma unroll
        for (int q = 0; q < 2; q++){
          load_lds16(gA[q] + k1, (void*)&As[nxt][ldsOff[q]]);
          load_lds16(gB[q] + k1, (void*)&Bs[nxt][ldsOff[q]]);
        }
        VM4();           // retire exactly tile t's 4 loads; t+1's stay in flight
      } else {
        VM0();           // last tile: nothing newer outstanding
      }
      BAR(); SB0();      // all waves' tile-t loads complete; pin reads after
      const int cA = (kc ^ rxor) << 3;
      bf16x8 af[4], bg[4];
      #pragma unroll
      for (int i=0;i<4;i++) af[i] = *(const bf16x8*)&As[cur][((wm + (i<<4) + fr) << 5) + cA];
      #pragma unroll
      for (int j=0;j<4;j++) bg[j] = *(const bf16x8*)&Bs[cur][((wn + (j<<4) + fr) << 5) + cA];
      #pragma unroll
      for (int i=0;i<4;i++)
        #pragma unroll
        for (int j=0;j<4;j++)
          acc[i][j] = __builtin_amdgcn_mfma_f32_16x16x32_bf16(af[i], bg[j], acc[i][j], 0, 0, 0);
      SB0(); BAR();      // all reads of buf cur done before its next overwrite
    }

    #pragma unroll
    for (int i=0;i<4;i++){
      #pragma unroll
      for (int reg=0;reg<4;reg++){
        int rl = wm + (i << 4) + cr + reg;
        int gm = m0 + rl;
        if (gm < ne){
          __bf16* hrow = h + (size_t)(base + gm) * HDIM + n0 + wn;
          #pragma unroll
          for (int j=0;j<4;j++){
            float v  = acc[i][j][reg];
            float sv = v / (1.0f + __expf(-v));
            unsigned short u = f2bfbits(sv);
            int part = __shfl_xor((int)u, 1, 64);
            if (!(lane & 1)){
              unsigned int packed = ((unsigned int)(unsigned short)part << 16) | u;
              *(unsigned int*)((unsigned short*)hrow + (j << 4) + cc) = packed;
            }
          }
        }
      }
    }
  }
}

// ---------------- GEMM2: 128x128, BK=64, 4 waves, 66KB LDS, 2 blocks/CU (R14 best) ----------------
__global__ __launch_bounds__(256, 2) void k_gemm2(const __bf16* __restrict__ h,
                                                  const __bf16* __restrict__ wdownT, // [E][D][H]
                                                  const int* __restrict__ offsets,
                                                  __bf16* __restrict__ y,
                                                  int elo){
  const int bid = blockIdx.x;                     // 2048 blocks per 32-expert group
  const int L   = ((bid & 7) << 8) | (bid >> 3);  // XCD k -> 4 whole experts
  const int e   = elo + (L >> 6);
  const int mb  = L & 7;
  const int nb  = (L >> 3) & 7;
  const int base = offsets[e];
  const int ne   = offsets[e + 1] - base;
  const int n0   = nb << 7;
  const int ybase = offsets[elo];

  __shared__ __align__(16) __bf16 As[2][128 * 64];
  __shared__ __align__(16) __bf16 Bs[2][128 * 64];

  const int tid = threadIdx.x;
  const int wave = tid >> 6, lane = tid & 63;
  const int wm = (wave >> 1) << 6;
  const int wn = (wave & 1) << 6;
  const int fr = lane & 15, kc = lane >> 4;
  const int rxor = fr & 7;
  const __bf16* wB = wdownT + (size_t)e * DDIM * HDIM + (size_t)n0 * HDIM;

  const int srl  = lane >> 3;                       // row-in-8
  const int scol = ((lane & 7) ^ srl) << 3;
  const __bf16* gB[4]; int ldsOff[4];
  #pragma unroll
  for (int q = 0; q < 4; q++){
    int r = (wave << 5) + (q << 3) + srl;
    gB[q] = wB + (size_t)r * HDIM + scol;
    ldsOff[q] = ((wave << 5) + (q << 3)) << 6;
  }

  const int cr = (lane >> 4) << 2, cc = lane & 15;

  for (int m0 = mb << 7; m0 < ne; m0 += 1024){
    const __bf16* gA[4];
    #pragma unroll
    for (int q = 0; q < 4; q++){
      int sl = m0 + (wave << 5) + (q << 3) + srl; if (sl >= ne) sl = ne - 1;
      gA[q] = h + (size_t)(base + sl) * HDIM + scol;
    }

    f32x4 acc[4][4];
    #pragma unroll
    for (int i=0;i<4;i++)
      #pragma unroll
      for (int j=0;j<4;j++) acc[i][j] = (f32x4){0.f,0.f,0.f,0.f};

    __syncthreads();
    #pragma unroll
    for (int q = 0; q < 4; q++){
      load_lds16(gA[q], (void*)&As[0][ldsOff[q]]);
      load_lds16(gB[q], (void*)&Bs[0][ldsOff[q]]);
    }
    __syncthreads();

    const int NK = HDIM / 64;
    for (int t = 0; t < NK; ++t){
      const int cur = t & 1;
      if (t + 1 < NK){
        const int k1 = (t + 1) << 6;
        const int nxt = cur ^ 1;
        #pragma unroll
        for (int q = 0; q < 4; q++){
          load_lds16(gA[q] + k1, (void*)&As[nxt][ldsOff[q]]);
          load_lds16(gB[q] + k1, (void*)&Bs[nxt][ldsOff[q]]);
        }
      }
      #pragma unroll
      for (int ks = 0; ks < 2; ks++){
        const int cA = (((ks << 2) + kc) ^ rxor) << 3;
        bf16x8 af[4], bg[4];
        #pragma unroll
        for (int i=0;i<4;i++) af[i] = *(const bf16x8*)&As[cur][((wm + (i<<4) + fr) << 6) + cA];
        #pragma unroll
        for (int j=0;j<4;j++) bg[j] = *(const bf16x8*)&Bs[cur][((wn + (j<<4) + fr) << 6) + cA];
        #pragma unroll
        for (int i=0;i<4;i++)
          #pragma unroll
          for (int j=0;j<4;j++)
            acc[i][j] = __builtin_amdgcn_mfma_f32_16x16x32_bf16(af[i], bg[j], acc[i][j], 0, 0, 0);
      }
      __syncthreads();
    }

    #pragma unroll
    for (int i=0;i<4;i++){
      #pragma unroll
      for (int reg=0;reg<4;reg++){
        int rl = wm + (i << 4) + cr + reg;
        int gm = m0 + rl;
        if (gm < ne){
          __bf16* yrow = y + (size_t)(base - ybase + gm) * DDIM + n0 + wn;
          #pragma unroll
          for (int j=0;j<4;j++){
            unsigned short u = f2bfbits(acc[i][j][reg]);
            int part = __shfl_xor((int)u, 1, 64);
            if (!(lane & 1)){
              unsigned int packed = ((unsigned int)(unsigned short)part << 16) | u;
              *(unsigned int*)((unsigned short*)yrow + (j << 4) + cc) = packed;
            }
          }
        }
      }
    }
  }
}

// ---------------- combine: out[t] (+)= sum_k w_k * y[pos(t,k)] for experts in [elo,ehi) ----------------
__global__ __launch_bounds__(256) void k_combine(const __bf16* __restrict__ y,
                                                 const int* __restrict__ tk_idx,
                                                 const float* __restrict__ tk_w,
                                                 const int* __restrict__ inv_pos,
                                                 const int* __restrict__ offsets,
                                                 float* __restrict__ out,
                                                 int elo, int ehi, int first){
  const int t   = blockIdx.x;
  const int tid = threadIdx.x;
  __shared__ int se[8]; __shared__ float sw[8]; __shared__ int sp[8];
  if (tid < 8){
    se[tid] = tk_idx[(size_t)t * 8 + tid];
    sw[tid] = tk_w [(size_t)t * 8 + tid];
    sp[tid] = inv_pos[(size_t)t * 8 + tid];
  }
  __syncthreads();
  const int ybase = offsets[elo];
  const int c = tid << 2;
  float4 acc;
  if (first) acc = make_float4(0.f, 0.f, 0.f, 0.f);
  else       acc = *(const float4*)&out[(size_t)t * DDIM + c];
  #pragma unroll
  for (int k = 0; k < 8; k++){
    int e = se[k];
    if (e >= elo && e < ehi){
      const unsigned short* yr = (const unsigned short*)y + (size_t)(sp[k] - ybase) * DDIM + c;
      ushort4 raw = *(const ushort4*)yr;
      float w = sw[k];
      acc.x += w * bf2f(raw.x);
      acc.y += w * bf2f(raw.y);
      acc.z += w * bf2f(raw.z);
      acc.w += w * bf2f(raw.w);
    }
  }
  *(float4*)&out[(size_t)t * DDIM + c] = acc;
}

// ---------------- host launch ----------------
extern "C" void kernel_launch(void* const* d_in, const int* in_sizes, int n_in,
                              void* d_out, int out_size, void* d_ws, size_t ws_size,
                              hipStream_t stream){
  const float* x     = (const float*)d_in[0];
  const float* Wg    = (const float*)d_in[1];
  const float* Wup   = (const float*)d_in[2];
  const float* Wdown = (const float*)d_in[3];
  float* out = (float*)d_out;

  char* ws = (char*)d_ws;
  size_t off = 0;
  auto alloc = [&](size_t bytes) -> void* {
    void* p = ws + off;
    off += (bytes + 255) & ~(size_t)255;
    return p;
  };
  // [wupT][xb][logits] are DEAD after k_gemm1; reused as the per-group y buffer.
  __bf16* wupT      = (__bf16*)alloc((size_t)NEXP * DDIM * HDIM * 2);  // 67.1 MB
  __bf16* xb        = (__bf16*)alloc((size_t)T_TOK * DDIM * 2);        // 16.8 MB
  float*  logits    = (float*)alloc((size_t)T_TOK * NEXP * 4);         //  2.1 MB
  __bf16* wdownT    = (__bf16*)alloc((size_t)NEXP * DDIM * HDIM * 2);  // 67.1 MB
  __bf16* hbuf      = (__bf16*)alloc((size_t)T_TOK * TOPK * HDIM * 2); // 67.1 MB
  int*    tk_idx    = (int*)  alloc((size_t)T_TOK * TOPK * 4);
  float*  tk_w      = (float*)alloc((size_t)T_TOK * TOPK * 4);
  int*    slot_tok  = (int*)  alloc((size_t)T_TOK * TOPK * 4);
  int*    inv_pos   = (int*)  alloc((size_t)T_TOK * TOPK * 4);
  int*    g_hist    = (int*)  alloc((size_t)CHUNKS * 64 * 4);
  int*    g_base    = (int*)  alloc((size_t)CHUNKS * 64 * 4);
  int*    offsets   = (int*)  alloc(512);
  __bf16* ybuf      = (__bf16*)ws;   // alias over wupT+xb+logits

  k_gate<<<T_TOK / 64, 256, 0, stream>>>(x, Wg, logits, xb);
  k_transpose_both<<<16384, 256, 0, stream>>>(Wdown, Wup, wdownT, wupT);
  k_topk<<<T_TOK / 4, 256, 0, stream>>>(logits, tk_idx, tk_w);
  k_hist<<<CHUNKS, 256, 0, stream>>>(tk_idx, g_hist);
  k_scan<<<1, 64, 0, stream>>>(g_hist, offsets, g_base);
  k_scatter<<<CHUNKS, 256, 0, stream>>>(tk_idx, g_base, slot_tok, inv_pos);
  // gemm1: 128x128 BK=32, 4 blocks/CU, counted-vmcnt 2-phase
  k_gemm1<<<2048, 256, 0, stream>>>(xb, wupT, offsets, slot_tok, hbuf);
  // gemm2: 128x128 BK=64, 2 blocks/CU, per 32-expert group
  k_gemm2<<<2048, 256, 0, stream>>>(hbuf, wdownT, offsets, ybuf, 0);
  k_combine<<<T_TOK, 256, 0, stream>>>(ybuf, tk_idx, tk_w, inv_pos, offsets, out, 0, 32, 1);
  k_gemm2<<<2048, 256, 0, stream>>>(hbuf, wdownT, offsets, ybuf, 32);
  k_combine<<<T_TOK, 256, 0, stream>>>(ybuf, tk_idx, tk_w, inv_pos, offsets, out, 32, 64, 0);
}